// Round 11
// baseline (1592.537 us; speedup 1.0000x reference)
//
#include <hip/hip_runtime.h>
#include <cstddef>
#include <cstdint>

#define NB 8
#define NPTS 4096
#define NS 1024
#define NK 32
#define ND 64

// ------------------------------------------------------------------
// FPS: one block per batch, 256 threads x 16 points (1 wave/SIMD).
// BARRIER-FREE main loop: per-iteration __syncthreads() replaced by an
// LDS tag protocol (entry write -> threadfence_block -> tag=s+1; spin
// on all 4 tags >= s+1; fence; read entries). Parity double-buffer is
// safe: publishing generation s+2 requires having observed tags>=s+2,
// which requires every wave consumed generation s (same parity).
// Wave reduce: DPP f32 max + ballot first-lane (smallest index);
// cross-wave: 4-entry tournament, strict >, earlier wave wins ties
// (disjoint ascending ranges -> jnp.argmax first-occurrence exactly).
// Distance arithmetic bit-exact vs numpy.
// ------------------------------------------------------------------
#define DPP_IMAX(v, ctrl)                                                     \
  {                                                                           \
    int _o = __builtin_amdgcn_update_dpp(v, v, ctrl, 0xf, 0xf, false);        \
    v = (_o > v) ? _o : v;                                                    \
  }

// group-of-8 sum via row_shr (lanes 7 mod 8 hold their group's sum)
#define DPP_FADD(v, ctrl)                                                     \
  {                                                                           \
    int _t = __builtin_amdgcn_update_dpp(__float_as_int(v), __float_as_int(v),\
                                         ctrl, 0xf, 0xf, false);              \
    v = v + __int_as_float(_t);                                               \
  }

__global__ __launch_bounds__(256, 1) void fps_kernel(const float* __restrict__ xyz,
                                                     float* __restrict__ out_newxyz,
                                                     float* __restrict__ ws_newxyz) {
  const int b = blockIdx.x;
  const int t = threadIdx.x;   // 0..255
  const int wave = t >> 6;     // 0..3
  const int lane = t & 63;
  __shared__ __align__(16) float4 sE[2][4];   // (dist, x, y, z) per wave
  __shared__ int sTag[4];                     // last published iteration+1
  __shared__ __align__(16) float4 sCent[NS];  // emitted centroids, 16 KB
  const float* xb = xyz + (size_t)b * 3 * NPTS;

  float px[16], py[16], pz[16], dist[16];
#pragma unroll
  for (int q = 0; q < 4; ++q) {
    float4 a = ((const float4*)xb)[4 * t + q];
    float4 bq = ((const float4*)(xb + NPTS))[4 * t + q];
    float4 c = ((const float4*)(xb + 2 * NPTS))[4 * t + q];
    px[4 * q + 0] = a.x;  px[4 * q + 1] = a.y;  px[4 * q + 2] = a.z;  px[4 * q + 3] = a.w;
    py[4 * q + 0] = bq.x; py[4 * q + 1] = bq.y; py[4 * q + 2] = bq.z; py[4 * q + 3] = bq.w;
    pz[4 * q + 0] = c.x;  pz[4 * q + 1] = c.y;  pz[4 * q + 2] = c.z;  pz[4 * q + 3] = c.w;
  }
#pragma unroll
  for (int j = 0; j < 16; ++j) dist[j] = 1e10f;

  if (lane == 0) sTag[wave] = 0;
  __syncthreads();  // one-time: tag init visible to all waves

  float cx = xb[0], cy = xb[NPTS], cz = xb[2 * NPTS];  // centroid 0
  volatile int* vt = (volatile int*)sTag;

  for (int s = 0; s < NS; ++s) {
    if (t == 0) sCent[s] = make_float4(cx, cy, cz, 0.f);  // off-chain
    // bit-exact dist update
#pragma unroll
    for (int j = 0; j < 16; ++j) {
      float dx = __fadd_rn(px[j], -cx);
      float dy = __fadd_rn(py[j], -cy);
      float dz = __fadd_rn(pz[j], -cz);
      float d = __fadd_rn(__fadd_rn(__fmul_rn(dx, dx), __fmul_rn(dy, dy)), __fmul_rn(dz, dz));
      dist[j] = fminf(dist[j], d);
    }
    float m0 = fmaxf(fmaxf(fmaxf(dist[0], dist[1]), fmaxf(dist[2], dist[3])),
                     fmaxf(fmaxf(dist[4], dist[5]), fmaxf(dist[6], dist[7])));
    float m1 = fmaxf(fmaxf(fmaxf(dist[8], dist[9]), fmaxf(dist[10], dist[11])),
                     fmaxf(fmaxf(dist[12], dist[13]), fmaxf(dist[14], dist[15])));
    float m = fmaxf(m0, m1);
    // wave max (nonneg floats: int order == float order)
    int v = __float_as_int(m);
    DPP_IMAX(v, 0x111)
    DPP_IMAX(v, 0x112)
    DPP_IMAX(v, 0x114)
    DPP_IMAX(v, 0x118)
    DPP_IMAX(v, 0x142)
    DPP_IMAX(v, 0x143)
    const int wm_i = __builtin_amdgcn_readlane(v, 63);
    const float wm = __int_as_float(wm_i);
    unsigned long long claim = __ballot(m == wm);
    int firstlane = __ffsll(claim) - 1;
    if (lane == firstlane) {
      int j = 15;
#pragma unroll
      for (int jj = 14; jj >= 0; --jj)
        if (dist[jj] == wm) j = jj;  // smallest matching j
      sE[s & 1][wave] = make_float4(wm, px[j], py[j], pz[j]);
    }
    __threadfence_block();              // entry visible before tag
    if (lane == 0) sTag[wave] = s + 1;  // publish
    // spin until all 4 waves published this generation
    while (vt[0] < s + 1 || vt[1] < s + 1 || vt[2] < s + 1 || vt[3] < s + 1) {}
    __threadfence_block();              // no entry read before spin exit
    float4 e0 = sE[s & 1][0], e1 = sE[s & 1][1];
    float4 e2 = sE[s & 1][2], e3 = sE[s & 1][3];
    float4 a01 = (e1.x > e0.x) ? e1 : e0;
    float4 a23 = (e3.x > e2.x) ? e3 : e2;
    float4 w4 = (a23.x > a01.x) ? a23 : a01;
    cx = w4.y;
    cy = w4.z;
    cz = w4.w;
  }
  __syncthreads();
  // dump centroids: out (B,3,S) and ws (b*S+s)*3
  for (int s2 = t; s2 < NS; s2 += 256) {
    float4 c = sCent[s2];
    out_newxyz[b * 3 * NS + s2] = c.x;
    out_newxyz[b * 3 * NS + NS + s2] = c.y;
    out_newxyz[b * 3 * NS + 2 * NS + s2] = c.z;
    ws_newxyz[((b << 10) + s2) * 3 + 0] = c.x;
    ws_newxyz[((b << 10) + s2) * 3 + 1] = c.y;
    ws_newxyz[((b << 10) + s2) * 3 + 2] = c.z;
  }
}

// ------------------------------------------------------------------
// Ball query (unchanged)
// ------------------------------------------------------------------
__global__ __launch_bounds__(256) void query_kernel(const float* __restrict__ xyz,
                                                    const float* __restrict__ ws_newxyz,
                                                    int* __restrict__ idx_ws) {
  const int w = threadIdx.x >> 6;
  const int lane = threadIdx.x & 63;
  const int p = blockIdx.x * 4 + w;  // 8192 pairs
  const int b = p >> 10;
  __shared__ int sIdx[4][32];
  const float* xb = xyz + (size_t)b * 3 * NPTS;
  const float cx = ws_newxyz[p * 3 + 0];
  const float cy = ws_newxyz[p * 3 + 1];
  const float cz = ws_newxyz[p * 3 + 2];
  const float ss = __fadd_rn(__fadd_rn(__fmul_rn(cx, cx), __fmul_rn(cy, cy)), __fmul_rn(cz, cz));
  const float r2 = (float)(0.4 * 0.4);
  int cnt = 0;
  for (int ci = 0; ci < 64 && cnt < 32; ++ci) {
    int n = ci * 64 + lane;
    float x = xb[n], y = xb[NPTS + n], z = xb[2 * NPTS + n];
    float dot = __fadd_rn(__fadd_rn(__fmul_rn(cx, x), __fmul_rn(cy, y)), __fmul_rn(cz, z));
    float dd = __fadd_rn(__fadd_rn(__fmul_rn(x, x), __fmul_rn(y, y)), __fmul_rn(z, z));
    float d = __fmul_rn(-2.0f, dot);
    d = __fadd_rn(d, ss);
    d = __fadd_rn(d, dd);
    d = fmaxf(d, 1e-12f);  // clip
    bool inc = (d <= r2);
    unsigned long long m = __ballot(inc);
    int slot = cnt + (int)__popcll(m & ((1ull << lane) - 1ull));
    if (inc && slot < 32) sIdx[w][slot] = n;
    cnt += (int)__popcll(m);
  }
  if (lane < 32) {
    int v;
    if (lane < cnt) v = sIdx[w][lane];
    else v = (cnt > 0) ? sIdx[w][0] : 0;
    idx_ws[p * 32 + lane] = v;
  }
}

// ------------------------------------------------------------------
// P1[b][n][o] = sum_c points[b][c][n] * W0[o][3+c] + b0[o]
// ------------------------------------------------------------------
__global__ __launch_bounds__(256) void pgemm_kernel(const float* __restrict__ points,
                                                    const float* __restrict__ W0,
                                                    const float* __restrict__ b0,
                                                    float* __restrict__ P1) {
  const int blk = blockIdx.x;  // 512 = 8 batches * 64 n-tiles
  const int b = blk >> 6;
  const int n0 = (blk & 63) * 64;
  const int t = threadIdx.x;
  __shared__ __align__(16) float sP[64 * 64];  // [c][n]
  __shared__ __align__(16) float sW[64 * 68];  // [c][o], pitch 68
  __shared__ float sB[64];
  const float* pb = points + (size_t)b * ND * NPTS;
  for (int f = t; f < 4096; f += 256) {
    int c = f >> 6, n = f & 63;
    sP[f] = pb[c * NPTS + n0 + n];
  }
  for (int f = t; f < 4096; f += 256) {
    int c = f >> 6, o = f & 63;
    sW[c * 68 + o] = W0[o * 67 + 3 + c];
  }
  if (t < 64) sB[t] = b0[t];
  __syncthreads();
  const int nl = (t & 15) * 4;
  const int ol = (t >> 4) * 4;
  float acc[4][4];
#pragma unroll
  for (int i = 0; i < 4; ++i)
#pragma unroll
    for (int j = 0; j < 4; ++j) acc[i][j] = 0.f;
#pragma unroll 4
  for (int c = 0; c < 64; ++c) {
    float4 xv = *(const float4*)(sP + c * 64 + nl);
    float4 wv = *(const float4*)(sW + c * 68 + ol);
    float xa[4] = {xv.x, xv.y, xv.z, xv.w};
    float wa[4] = {wv.x, wv.y, wv.z, wv.w};
#pragma unroll
    for (int i = 0; i < 4; ++i)
#pragma unroll
      for (int j = 0; j < 4; ++j) acc[i][j] += xa[i] * wa[j];
  }
#pragma unroll
  for (int i = 0; i < 4; ++i) {
    float4 v = make_float4(acc[i][0] + sB[ol + 0], acc[i][1] + sB[ol + 1],
                           acc[i][2] + sB[ol + 2], acc[i][3] + sB[ol + 3]);
    *(float4*)(P1 + ((size_t)(b << 12) + n0 + nl + i) * 64 + ol) = v;
  }
}

// ------------------------------------------------------------------
// Layer-0 via gather of P1 rows (unchanged)
// ------------------------------------------------------------------
__global__ __launch_bounds__(256) void gather0_kernel(
    const float* __restrict__ xyz, const float* __restrict__ P1,
    const int* __restrict__ idx_ws, const float* __restrict__ cen_ws,
    const float* __restrict__ W0, float* __restrict__ y0,
    float* __restrict__ partials) {
  const int t = threadIdx.x;
  const int wave = t >> 6, lane = t & 63;
  const int pair0 = blockIdx.x * 2;
  const int b = pair0 >> 10;
  __shared__ int sIdx[64];
  __shared__ float sCen[2 * 4];
  __shared__ float sY[64 * 65];  // [row r=(sl*32+k)][o], pitch 65
  __shared__ float sWS[4 * 64];
  __shared__ float sWQ[4 * 64];
  if (t < 64) sIdx[t] = idx_ws[pair0 * 32 + t];
  if (t < 6) sCen[(t / 3) * 4 + (t % 3)] = cen_ws[pair0 * 3 + t];
  const float wx = W0[lane * 67 + 0];
  const float wy = W0[lane * 67 + 1];
  const float wz = W0[lane * 67 + 2];
  __syncthreads();
  const float* xb = xyz + (size_t)b * 3 * NPTS;
  float ssum = 0.f, ssq = 0.f;
  for (int r = wave; r < 64; r += 4) {
    const int sl = r >> 5;
    const int n = sIdx[r];
    float P1v = P1[((size_t)(b << 12) + n) * 64 + lane];
    float dx = __fadd_rn(xb[n], -sCen[sl * 4 + 0]);
    float dy = __fadd_rn(xb[NPTS + n], -sCen[sl * 4 + 1]);
    float dz = __fadd_rn(xb[2 * NPTS + n], -sCen[sl * 4 + 2]);
    float y = P1v + (dx * wx + dy * wy + dz * wz);
    ssum += y;
    ssq += y * y;
    sY[r * 65 + lane] = y;
  }
  sWS[wave * 64 + lane] = ssum;
  sWQ[wave * 64 + lane] = ssq;
  __syncthreads();
  for (int f = t; f < 4096; f += 256) {
    int sl = f >> 11;
    int rmd = f & 2047;
    int o = rmd >> 5, k = rmd & 31;
    y0[(size_t)(pair0 + sl) * 2048 + rmd] = sY[(sl * 32 + k) * 65 + o];
  }
  if (t < 64) {
    float s1 = sWS[t] + sWS[64 + t] + sWS[128 + t] + sWS[192 + t];
    float s2 = sWQ[t] + sWQ[64 + t] + sWQ[128 + t] + sWQ[192 + t];
    partials[(size_t)blockIdx.x * 128 + t] = s1;
    partials[(size_t)blockIdx.x * 128 + 64 + t] = s2;
  }
}

// ------------------------------------------------------------------
// Conv + bias + BN-stat partials. Stats via DPP group-of-8 pre-reduce.
// MODE 1: write y. MODE 2: max/min-pool.
// ------------------------------------------------------------------
template <int CIN, int COUT, int SPB, int MODE>
__global__ __launch_bounds__(256) void conv_kernel(
    const float* __restrict__ xin, const float* __restrict__ W,
    const float* __restrict__ bias, const float* __restrict__ scaleA,
    const float* __restrict__ shiftA, float* __restrict__ yout,
    float* __restrict__ pmax, float* __restrict__ pmin,
    float* __restrict__ partials) {
  constexpr int WP = COUT + 4;
  constexpr int TPS = (COUT / 4) * 8;
  __shared__ __align__(16) float sW[CIN * WP];
  __shared__ __align__(16) float sX[SPB * CIN * 32];
  __shared__ float sScale[CIN];
  __shared__ float sShift[CIN];
  __shared__ float sSum[COUT];
  __shared__ float sSq[COUT];
  __shared__ float sMax[8 * COUT];
  __shared__ float sMin[8 * COUT];

  const int t = threadIdx.x;
  const int pair0 = blockIdx.x * SPB;

  for (int f = t; f < CIN * COUT; f += 256) {
    int o = f / CIN;
    int c = f - o * CIN;
    sW[c * WP + o] = W[f];
  }
  if (t < CIN) { sScale[t] = scaleA[t]; sShift[t] = shiftA[t]; }
  if (t < COUT) { sSum[t] = 0.f; sSq[t] = 0.f; }
  __syncthreads();

  for (int f = t; f < SPB * CIN * 32; f += 256) {
    int c = (f >> 5) % CIN;
    float v = xin[(size_t)pair0 * CIN * 32 + f];
    v = v * sScale[c] + sShift[c];
    sX[f] = fmaxf(v, 0.f);
  }
  __syncthreads();

  const int sl = t / TPS;
  const int tl = t - sl * TPS;
  const int k0 = (tl & 7) * 4;
  const int o0 = (tl >> 3) * 4;

  float acc[4][4];
#pragma unroll
  for (int i = 0; i < 4; ++i)
#pragma unroll
    for (int j = 0; j < 4; ++j) acc[i][j] = 0.f;

  const float* xrow = sX + sl * (CIN * 32);
#pragma unroll 4
  for (int c = 0; c < CIN; ++c) {
    float4 xv = *(const float4*)(xrow + c * 32 + k0);
    float4 wv = *(const float4*)(sW + c * WP + o0);
    float xa[4] = {xv.x, xv.y, xv.z, xv.w};
    float wa[4] = {wv.x, wv.y, wv.z, wv.w};
#pragma unroll
    for (int i = 0; i < 4; ++i)
#pragma unroll
      for (int j = 0; j < 4; ++j) acc[i][j] += wa[i] * xa[j];
  }
#pragma unroll
  for (int i = 0; i < 4; ++i) {
    float bo = bias[o0 + i];
#pragma unroll
    for (int j = 0; j < 4; ++j) acc[i][j] += bo;
  }
#pragma unroll
  for (int i = 0; i < 4; ++i) {
    float s1 = (acc[i][0] + acc[i][1]) + (acc[i][2] + acc[i][3]);
    float s2 = (acc[i][0] * acc[i][0] + acc[i][1] * acc[i][1]) +
               (acc[i][2] * acc[i][2] + acc[i][3] * acc[i][3]);
    DPP_FADD(s1, 0x111)
    DPP_FADD(s1, 0x112)
    DPP_FADD(s1, 0x114)
    DPP_FADD(s2, 0x111)
    DPP_FADD(s2, 0x112)
    DPP_FADD(s2, 0x114)
    if ((t & 7) == 7) {
      atomicAdd(&sSum[o0 + i], s1);
      atomicAdd(&sSq[o0 + i], s2);
    }
  }
  if (MODE < 2) {
#pragma unroll
    for (int i = 0; i < 4; ++i) {
      float4 v = make_float4(acc[i][0], acc[i][1], acc[i][2], acc[i][3]);
      *(float4*)(yout + (size_t)(pair0 + sl) * COUT * 32 + (o0 + i) * 32 + k0) = v;
    }
  } else {
#pragma unroll
    for (int i = 0; i < 4; ++i) {
      float mx = fmaxf(fmaxf(acc[i][0], acc[i][1]), fmaxf(acc[i][2], acc[i][3]));
      float mn = fminf(fminf(acc[i][0], acc[i][1]), fminf(acc[i][2], acc[i][3]));
      sMax[(k0 >> 2) * COUT + o0 + i] = mx;
      sMin[(k0 >> 2) * COUT + o0 + i] = mn;
    }
  }
  __syncthreads();
  if (t < COUT) {
    partials[(size_t)blockIdx.x * (COUT * 2) + t] = sSum[t];
    partials[(size_t)blockIdx.x * (COUT * 2) + COUT + t] = sSq[t];
    if (MODE == 2) {
      float mx = sMax[t];
      float mn = sMin[t];
#pragma unroll
      for (int q = 1; q < 8; ++q) {
        mx = fmaxf(mx, sMax[q * COUT + t]);
        mn = fminf(mn, sMin[q * COUT + t]);
      }
      pmax[pair0 * COUT + t] = mx;
      pmin[pair0 * COUT + t] = mn;
    }
  }
}

// one block per channel: f64 reduce -> fused scale/shift for next layer
template <int COUT>
__global__ __launch_bounds__(256) void stats_kernel(const float* __restrict__ partials,
                                                    int nblocks,
                                                    const float* __restrict__ gA,
                                                    const float* __restrict__ btA,
                                                    float* __restrict__ scaleA,
                                                    float* __restrict__ shiftA) {
  const int o = blockIdx.x;
  const int t = threadIdx.x;
  double s1 = 0.0, s2 = 0.0;
  for (int blk = t; blk < nblocks; blk += 256) {
    s1 += (double)partials[(size_t)blk * (COUT * 2) + o];
    s2 += (double)partials[(size_t)blk * (COUT * 2) + COUT + o];
  }
  __shared__ double r1[256], r2[256];
  r1[t] = s1; r2[t] = s2;
  __syncthreads();
  for (int st = 128; st > 0; st >>= 1) {
    if (t < st) { r1[t] += r1[t + st]; r2[t] += r2[t + st]; }
    __syncthreads();
  }
  if (t == 0) {
    const double Nr = 262144.0;  // B*K*S
    double mean = r1[0] / Nr;
    double var = r2[0] / Nr - mean * mean;
    double rstd = 1.0 / sqrt(var + 1e-5);
    double sc = rstd * (double)gA[o];
    scaleA[o] = (float)sc;
    shiftA[o] = (float)((double)btA[o] - mean * sc);
  }
}

// layer-2 stats + final normalize fused: one block per channel (128).
__global__ __launch_bounds__(256) void stats_final_kernel(
    const float* __restrict__ partials, int nblocks,
    const float* __restrict__ pmax, const float* __restrict__ pmin,
    const float* __restrict__ gA, const float* __restrict__ btA,
    float* __restrict__ out) {
  const int o = blockIdx.x;
  const int t = threadIdx.x;
  double s1 = 0.0, s2 = 0.0;
  for (int blk = t; blk < nblocks; blk += 256) {
    s1 += (double)partials[(size_t)blk * 256 + o];
    s2 += (double)partials[(size_t)blk * 256 + 128 + o];
  }
  __shared__ double r1[256], r2[256];
  __shared__ float sMean, sRstd;
  r1[t] = s1; r2[t] = s2;
  __syncthreads();
  for (int st = 128; st > 0; st >>= 1) {
    if (t < st) { r1[t] += r1[t + st]; r2[t] += r2[t + st]; }
    __syncthreads();
  }
  if (t == 0) {
    const double Nr = 262144.0;
    double mean = r1[0] / Nr;
    double var = r2[0] / Nr - mean * mean;
    sMean = (float)mean;
    sRstd = (float)(1.0 / sqrt(var + 1e-5));
  }
  __syncthreads();
  const float mn = sMean, rs = sRstd, gg = gA[o], bb = btA[o];
  const float slope = rs * gg;
  const float* src = (slope >= 0.f) ? pmax : pmin;
  for (int i = t; i < NB * NS; i += 256) {
    int b = i >> 10;
    int s = i & 1023;
    float v = src[(size_t)i * 128 + o];
    float t1 = (v - mn) * rs;
    float t2 = t1 * gg + bb;
    out[(size_t)b * (128 * NS) + o * NS + s] = fmaxf(t2, 0.f);
  }
}

extern "C" void kernel_launch(void* const* d_in, const int* in_sizes, int n_in,
                              void* d_out, int out_size, void* d_ws, size_t ws_size,
                              hipStream_t stream) {
  (void)in_sizes; (void)n_in; (void)out_size; (void)ws_size;
  const float* xyz = (const float*)d_in[0];
  const float* points = (const float*)d_in[1];
  const float* W0 = (const float*)d_in[2];
  const float* b0 = (const float*)d_in[3];
  const float* g0 = (const float*)d_in[4];
  const float* bt0 = (const float*)d_in[5];
  const float* W1 = (const float*)d_in[6];
  const float* b1 = (const float*)d_in[7];
  const float* g1 = (const float*)d_in[8];
  const float* bt1 = (const float*)d_in[9];
  const float* W2 = (const float*)d_in[10];
  const float* b2 = (const float*)d_in[11];
  const float* g2 = (const float*)d_in[12];
  const float* bt2 = (const float*)d_in[13];
  float* out = (float*)d_out;

  float* ws = (float*)d_ws;
  size_t off = 0;
  float* newxyz = ws + off;  off += (size_t)NB * NS * 3;
  int* idx = (int*)(ws + off); off += (size_t)NB * NS * NK;
  float* y0 = ws + off;      off += (size_t)NB * NS * 64 * 32;
  float* y1 = ws + off;      off += (size_t)NB * NS * 64 * 32;  // P1 aliases y1
  float* partials = ws + off; off += (size_t)8192 * 256;
  float* scaleA = ws + off;  off += 128;
  float* shiftA = ws + off;  off += 128;
  float* pmaxb = ws + off;   off += (size_t)NB * NS * 128;
  float* pminb = ws + off;   off += (size_t)NB * NS * 128;
  float* P1 = y1;  // P1 (2M floats) dead before conv1 writes y1

  fps_kernel<<<NB, 256, 0, stream>>>(xyz, out, newxyz);
  query_kernel<<<2048, 256, 0, stream>>>(xyz, newxyz, idx);
  pgemm_kernel<<<512, 256, 0, stream>>>(points, W0, b0, P1);
  gather0_kernel<<<4096, 256, 0, stream>>>(xyz, P1, idx, newxyz, W0, y0, partials);
  stats_kernel<64><<<64, 256, 0, stream>>>(partials, 4096, g0, bt0, scaleA, shiftA);
  conv_kernel<64, 64, 2, 1><<<4096, 256, 0, stream>>>(
      y0, W1, b1, scaleA, shiftA, y1, nullptr, nullptr, partials);
  stats_kernel<64><<<64, 256, 0, stream>>>(partials, 4096, g1, bt1, scaleA, shiftA);
  conv_kernel<64, 128, 1, 2><<<8192, 256, 0, stream>>>(
      y1, W2, b2, scaleA, shiftA, nullptr, pmaxb, pminb, partials);
  stats_final_kernel<<<128, 256, 0, stream>>>(partials, 8192, pmaxb, pminb,
                                              g2, bt2, out + NB * NS * 3);
}

// Round 12
// 1043.061 us; speedup vs baseline: 1.5268x; 1.5268x over previous
//
#include <hip/hip_runtime.h>
#include <cstddef>
#include <cstdint>

#define NB 8
#define NPTS 4096
#define NS 1024
#define NK 32
#define ND 64

// ------------------------------------------------------------------
// fps+pgemm hetero-grid kernel. Blocks 0..7: FPS (R6 structure, best
// measured 725 us — fps is latency-floored; do not touch). Blocks
// 8..519: pgemm on otherwise-idle CUs (hidden under fps). Shared-LDS
// union; every thread of a block reaches its branch's barriers.
// ------------------------------------------------------------------
#define DPP_IMAX(v, ctrl)                                                     \
  {                                                                           \
    int _o = __builtin_amdgcn_update_dpp(v, v, ctrl, 0xf, 0xf, false);        \
    v = (_o > v) ? _o : v;                                                    \
  }

#define DPP_U64MAX(hi, lo, ctrl)                                              \
  {                                                                           \
    unsigned _nh = (unsigned)__builtin_amdgcn_update_dpp((int)(hi), (int)(hi),\
                                                         ctrl, 0xf, 0xf, false);\
    unsigned _nl = (unsigned)__builtin_amdgcn_update_dpp((int)(lo), (int)(lo),\
                                                         ctrl, 0xf, 0xf, false);\
    bool _gt = (_nh > (hi)) || (_nh == (hi) && _nl > (lo));                   \
    hi = _gt ? _nh : (hi);                                                    \
    lo = _gt ? _nl : (lo);                                                    \
  }

// group-of-8 sum via row_shr (lanes 7 mod 8 hold their group's sum)
#define DPP_FADD(v, ctrl)                                                     \
  {                                                                           \
    int _t = __builtin_amdgcn_update_dpp(__float_as_int(v), __float_as_int(v),\
                                         ctrl, 0xf, 0xf, false);              \
    v = v + __int_as_float(_t);                                               \
  }

__global__ __launch_bounds__(512) void fps_pgemm_kernel(
    const float* __restrict__ xyz, float* __restrict__ out_newxyz,
    float* __restrict__ ws_newxyz, const float* __restrict__ points,
    const float* __restrict__ W0, const float* __restrict__ b0g,
    float* __restrict__ P1) {
  __shared__ __align__(16) char smem[53376];
  const int t = threadIdx.x;

  if (blockIdx.x < 8) {
    // ---------------- FPS ----------------
    float* sXYZ = (float*)smem;                                    // 49152 B
    unsigned long long(*sRed)[8] =
        (unsigned long long(*)[8])(smem + 49152);                  // 128 B
    int* sWidx = (int*)(smem + 49280);                             // 4096 B
    const int b = blockIdx.x;
    const int wave = t >> 6;
    const int lane = t & 63;
    const float* xb = xyz + (size_t)b * 3 * NPTS;

    for (int i = t; i < NPTS; i += 512) {
      sXYZ[i * 3 + 0] = xb[i];
      sXYZ[i * 3 + 1] = xb[NPTS + i];
      sXYZ[i * 3 + 2] = xb[2 * NPTS + i];
    }
    if (t == 0) sWidx[0] = 0;

    float px[8], py[8], pz[8], dist[8];
    {
      float4 a0 = ((const float4*)xb)[2 * t];
      float4 a1 = ((const float4*)xb)[2 * t + 1];
      float4 b0v = ((const float4*)(xb + NPTS))[2 * t];
      float4 b1v = ((const float4*)(xb + NPTS))[2 * t + 1];
      float4 c0 = ((const float4*)(xb + 2 * NPTS))[2 * t];
      float4 c1 = ((const float4*)(xb + 2 * NPTS))[2 * t + 1];
      px[0] = a0.x; px[1] = a0.y; px[2] = a0.z; px[3] = a0.w;
      px[4] = a1.x; px[5] = a1.y; px[6] = a1.z; px[7] = a1.w;
      py[0] = b0v.x; py[1] = b0v.y; py[2] = b0v.z; py[3] = b0v.w;
      py[4] = b1v.x; py[5] = b1v.y; py[6] = b1v.z; py[7] = b1v.w;
      pz[0] = c0.x; pz[1] = c0.y; pz[2] = c0.z; pz[3] = c0.w;
      pz[4] = c1.x; pz[5] = c1.y; pz[6] = c1.z; pz[7] = c1.w;
    }
#pragma unroll
    for (int j = 0; j < 8; ++j) dist[j] = 1e10f;

    float cx = xb[0], cy = xb[NPTS], cz = xb[2 * NPTS];  // centroid 0

    for (int s = 0; s < NS; ++s) {
#pragma unroll
      for (int j = 0; j < 8; ++j) {
        float dx = __fadd_rn(px[j], -cx);
        float dy = __fadd_rn(py[j], -cy);
        float dz = __fadd_rn(pz[j], -cz);
        float d = __fadd_rn(__fadd_rn(__fmul_rn(dx, dx), __fmul_rn(dy, dy)),
                            __fmul_rn(dz, dz));
        dist[j] = fminf(dist[j], d);
      }
      float m = fmaxf(fmaxf(fmaxf(dist[0], dist[1]), fmaxf(dist[2], dist[3])),
                      fmaxf(fmaxf(dist[4], dist[5]), fmaxf(dist[6], dist[7])));
      int v = __float_as_int(m);
      DPP_IMAX(v, 0x111)
      DPP_IMAX(v, 0x112)
      DPP_IMAX(v, 0x114)
      DPP_IMAX(v, 0x118)
      DPP_IMAX(v, 0x142)
      DPP_IMAX(v, 0x143)
      const int wm_i = __builtin_amdgcn_readlane(v, 63);
      const float wm = __int_as_float(wm_i);
      unsigned long long claim = __ballot(m == wm);
      int firstlane = __ffsll(claim) - 1;
      if (lane == firstlane) {
        int j = 7;
#pragma unroll
        for (int jj = 6; jj >= 0; --jj)
          if (dist[jj] == wm) j = jj;
        unsigned widx = (unsigned)(t * 8 + j);
        sRed[s & 1][wave] = ((unsigned long long)(unsigned)wm_i << 32) |
                            (unsigned long long)(0xFFFFFFFFu - widx);
      }
      __syncthreads();
      unsigned long long k = sRed[s & 1][lane & 7];
      unsigned h2 = (unsigned)(k >> 32), l2 = (unsigned)k;
      DPP_U64MAX(h2, l2, 0x111)
      DPP_U64MAX(h2, l2, 0x112)
      DPP_U64MAX(h2, l2, 0x114)
      const unsigned gl = (unsigned)__builtin_amdgcn_readlane((int)l2, 7);
      const int widx = (int)(0xFFFFFFFFu - gl);
      cx = sXYZ[widx * 3 + 0];
      cy = sXYZ[widx * 3 + 1];
      cz = sXYZ[widx * 3 + 2];
      if (t == 0 && s < NS - 1) sWidx[s + 1] = widx;
    }
    __syncthreads();
    for (int s2 = t; s2 < NS; s2 += 512) {
      int w = sWidx[s2];
      float x = sXYZ[w * 3 + 0], y = sXYZ[w * 3 + 1], z = sXYZ[w * 3 + 2];
      out_newxyz[b * 3 * NS + s2] = x;
      out_newxyz[b * 3 * NS + NS + s2] = y;
      out_newxyz[b * 3 * NS + 2 * NS + s2] = z;
      ws_newxyz[((b << 10) + s2) * 3 + 0] = x;
      ws_newxyz[((b << 10) + s2) * 3 + 1] = y;
      ws_newxyz[((b << 10) + s2) * 3 + 2] = z;
    }
  } else {
    // ---------------- pgemm: P1[b][n][o] = points·W0[:,3:] + b0 ----------
    float* sP = (float*)smem;            // 16384 B  [c][n]
    float* sW = (float*)(smem + 16384);  // 17408 B  [c][o] pitch 68
    float* sB = (float*)(smem + 33792);  // 256 B
    const int blk = blockIdx.x - 8;      // 0..511
    const int bb = blk >> 6;
    const int n0 = (blk & 63) * 64;
    const float* pb = points + (size_t)bb * ND * NPTS;
    for (int f = t; f < 4096; f += 512) {
      int c = f >> 6, n = f & 63;
      sP[f] = pb[c * NPTS + n0 + n];
    }
    for (int f = t; f < 4096; f += 512) {
      int c = f >> 6, o = f & 63;
      sW[c * 68 + o] = W0[o * 67 + 3 + c];
    }
    if (t < 64) sB[t] = b0g[t];
    __syncthreads();
    if (t < 256) {
      const int nl = (t & 15) * 4;
      const int ol = (t >> 4) * 4;
      float acc[4][4];
#pragma unroll
      for (int i = 0; i < 4; ++i)
#pragma unroll
        for (int j = 0; j < 4; ++j) acc[i][j] = 0.f;
#pragma unroll 4
      for (int c = 0; c < 64; ++c) {
        float4 xv = *(const float4*)(sP + c * 64 + nl);
        float4 wv = *(const float4*)(sW + c * 68 + ol);
        float xa[4] = {xv.x, xv.y, xv.z, xv.w};
        float wa[4] = {wv.x, wv.y, wv.z, wv.w};
#pragma unroll
        for (int i = 0; i < 4; ++i)
#pragma unroll
          for (int j = 0; j < 4; ++j) acc[i][j] += xa[i] * wa[j];
      }
#pragma unroll
      for (int i = 0; i < 4; ++i) {
        float4 v = make_float4(acc[i][0] + sB[ol + 0], acc[i][1] + sB[ol + 1],
                               acc[i][2] + sB[ol + 2], acc[i][3] + sB[ol + 3]);
        *(float4*)(P1 + ((size_t)(bb << 12) + n0 + nl + i) * 64 + ol) = v;
      }
    }
  }
}

// ------------------------------------------------------------------
// Ball query + layer-0 gather stats fused: one wave per (b,s). After
// resolving the 32 neighbor indices (kept in LDS), the wave gathers
// P1 rows (lane = channel, coalesced 256B) and accumulates layer-0
// sum/sumsq partials — y0 is never materialized.
// ------------------------------------------------------------------
__global__ __launch_bounds__(256) void query_gstats_kernel(
    const float* __restrict__ xyz, const float* __restrict__ ws_newxyz,
    const float* __restrict__ P1, const float* __restrict__ W0,
    int* __restrict__ idx_ws, float* __restrict__ partials) {
  const int w = threadIdx.x >> 6;
  const int lane = threadIdx.x & 63;
  const int p = blockIdx.x * 4 + w;  // 8192 pairs
  const int b = p >> 10;
  __shared__ int sIdx[4][32];
  __shared__ float sWS[4][64];
  __shared__ float sWQ[4][64];
  const float* xb = xyz + (size_t)b * 3 * NPTS;
  const float cx = ws_newxyz[p * 3 + 0];
  const float cy = ws_newxyz[p * 3 + 1];
  const float cz = ws_newxyz[p * 3 + 2];
  const float ss = __fadd_rn(__fadd_rn(__fmul_rn(cx, cx), __fmul_rn(cy, cy)), __fmul_rn(cz, cz));
  const float r2 = (float)(0.4 * 0.4);
  int cnt = 0;
  for (int ci = 0; ci < 64 && cnt < 32; ++ci) {
    int n = ci * 64 + lane;
    float x = xb[n], y = xb[NPTS + n], z = xb[2 * NPTS + n];
    float dot = __fadd_rn(__fadd_rn(__fmul_rn(cx, x), __fmul_rn(cy, y)), __fmul_rn(cz, z));
    float dd = __fadd_rn(__fadd_rn(__fmul_rn(x, x), __fmul_rn(y, y)), __fmul_rn(z, z));
    float d = __fmul_rn(-2.0f, dot);
    d = __fadd_rn(d, ss);
    d = __fadd_rn(d, dd);
    d = fmaxf(d, 1e-12f);  // clip
    bool inc = (d <= r2);
    unsigned long long m = __ballot(inc);
    int slot = cnt + (int)__popcll(m & ((1ull << lane) - 1ull));
    if (inc && slot < 32) sIdx[w][slot] = n;
    cnt += (int)__popcll(m);
  }
  if (lane < 32) {
    int v;
    if (lane < cnt) v = sIdx[w][lane];
    else v = (cnt > 0) ? sIdx[w][0] : 0;
    idx_ws[p * 32 + lane] = v;
    sIdx[w][lane] = v;  // resolved index table for gstats (wave-local)
  }
  // ---- gstats: lane = output channel ----
  const float wx = W0[lane * 67 + 0];
  const float wy = W0[lane * 67 + 1];
  const float wz = W0[lane * 67 + 2];
  float ssum = 0.f, ssq = 0.f;
  for (int r = 0; r < 32; ++r) {
    const int n = sIdx[w][r];
    float P1v = P1[((size_t)(b << 12) + n) * 64 + lane];
    float dx = __fadd_rn(xb[n], -cx);
    float dy = __fadd_rn(xb[NPTS + n], -cy);
    float dz = __fadd_rn(xb[2 * NPTS + n], -cz);
    float y = P1v + (dx * wx + dy * wy + dz * wz);
    ssum += y;
    ssq += y * y;
  }
  sWS[w][lane] = ssum;
  sWQ[w][lane] = ssq;
  __syncthreads();
  const int t = threadIdx.x;
  if (t < 64) {
    float s1 = sWS[0][t] + sWS[1][t] + sWS[2][t] + sWS[3][t];
    float s2 = sWQ[0][t] + sWQ[1][t] + sWQ[2][t] + sWQ[3][t];
    partials[(size_t)blockIdx.x * 128 + t] = s1;
    partials[(size_t)blockIdx.x * 128 + 64 + t] = s2;
  }
}

// ------------------------------------------------------------------
// conv1 with gather-recompute staging: recomputes layer-0 y (identical
// arithmetic to gstats), applies relu(y*scale+shift), GEMMs with W1,
// writes y1 + layer-1 stat partials. y0 never touches HBM.
// ------------------------------------------------------------------
__global__ __launch_bounds__(256) void conv1_kernel(
    const float* __restrict__ xyz, const float* __restrict__ P1,
    const int* __restrict__ idx_ws, const float* __restrict__ cen_ws,
    const float* __restrict__ W0, const float* __restrict__ W1,
    const float* __restrict__ bias, const float* __restrict__ scaleA,
    const float* __restrict__ shiftA, float* __restrict__ y1,
    float* __restrict__ partials) {
  constexpr int CIN = 64, COUT = 64, WP = 68, TPS = 128;
  __shared__ __align__(16) float sW[CIN * WP];
  __shared__ __align__(16) float sX[2 * CIN * 32];
  __shared__ float sY[64 * 65];  // [row r=(sl*32+k)][o], pitch 65
  __shared__ int sIdx[64];
  __shared__ float sCen[2 * 4];
  __shared__ float sScale[CIN];
  __shared__ float sShift[CIN];
  __shared__ float sSum[COUT];
  __shared__ float sSq[COUT];

  const int t = threadIdx.x;
  const int wave = t >> 6, lane = t & 63;
  const int pair0 = blockIdx.x * 2;
  const int b = pair0 >> 10;

  for (int f = t; f < CIN * COUT; f += 256) {
    int o = f / CIN;
    int c = f - o * CIN;
    sW[c * WP + o] = W1[f];
  }
  if (t < CIN) { sScale[t] = scaleA[t]; sShift[t] = shiftA[t]; }
  if (t < COUT) { sSum[t] = 0.f; sSq[t] = 0.f; }
  if (t < 64) sIdx[t] = idx_ws[pair0 * 32 + t];
  if (t < 6) sCen[(t / 3) * 4 + (t % 3)] = cen_ws[pair0 * 3 + t];
  const float wx = W0[lane * 67 + 0];
  const float wy = W0[lane * 67 + 1];
  const float wz = W0[lane * 67 + 2];
  __syncthreads();
  const float* xb = xyz + (size_t)b * 3 * NPTS;
  for (int r = wave; r < 64; r += 4) {
    const int sl = r >> 5;
    const int n = sIdx[r];
    float P1v = P1[((size_t)(b << 12) + n) * 64 + lane];
    float dx = __fadd_rn(xb[n], -sCen[sl * 4 + 0]);
    float dy = __fadd_rn(xb[NPTS + n], -sCen[sl * 4 + 1]);
    float dz = __fadd_rn(xb[2 * NPTS + n], -sCen[sl * 4 + 2]);
    sY[r * 65 + lane] = P1v + (dx * wx + dy * wy + dz * wz);
  }
  __syncthreads();
  // transpose + bn + relu into [c][k] layout (both sides conflict-free)
  for (int f = t; f < 2 * CIN * 32; f += 256) {
    int sl = f >> 11;
    int rmd = f & 2047;
    int o = rmd >> 5, k = rmd & 31;
    float v = sY[(sl * 32 + k) * 65 + o];
    v = v * sScale[o] + sShift[o];
    sX[f] = fmaxf(v, 0.f);
  }
  __syncthreads();

  const int sl = t / TPS;
  const int tl = t - sl * TPS;
  const int k0 = (tl & 7) * 4;
  const int o0 = (tl >> 3) * 4;

  float acc[4][4];
#pragma unroll
  for (int i = 0; i < 4; ++i)
#pragma unroll
    for (int j = 0; j < 4; ++j) acc[i][j] = 0.f;

  const float* xrow = sX + sl * (CIN * 32);
#pragma unroll 4
  for (int c = 0; c < CIN; ++c) {
    float4 xv = *(const float4*)(xrow + c * 32 + k0);
    float4 wv = *(const float4*)(sW + c * WP + o0);
    float xa[4] = {xv.x, xv.y, xv.z, xv.w};
    float wa[4] = {wv.x, wv.y, wv.z, wv.w};
#pragma unroll
    for (int i = 0; i < 4; ++i)
#pragma unroll
      for (int j = 0; j < 4; ++j) acc[i][j] += wa[i] * xa[j];
  }
#pragma unroll
  for (int i = 0; i < 4; ++i) {
    float bo = bias[o0 + i];
#pragma unroll
    for (int j = 0; j < 4; ++j) acc[i][j] += bo;
  }
#pragma unroll
  for (int i = 0; i < 4; ++i) {
    float s1 = (acc[i][0] + acc[i][1]) + (acc[i][2] + acc[i][3]);
    float s2 = (acc[i][0] * acc[i][0] + acc[i][1] * acc[i][1]) +
               (acc[i][2] * acc[i][2] + acc[i][3] * acc[i][3]);
    DPP_FADD(s1, 0x111)
    DPP_FADD(s1, 0x112)
    DPP_FADD(s1, 0x114)
    DPP_FADD(s2, 0x111)
    DPP_FADD(s2, 0x112)
    DPP_FADD(s2, 0x114)
    if ((t & 7) == 7) {
      atomicAdd(&sSum[o0 + i], s1);
      atomicAdd(&sSq[o0 + i], s2);
    }
  }
#pragma unroll
  for (int i = 0; i < 4; ++i) {
    float4 v = make_float4(acc[i][0], acc[i][1], acc[i][2], acc[i][3]);
    *(float4*)(y1 + (size_t)(pair0 + sl) * COUT * 32 + (o0 + i) * 32 + k0) = v;
  }
  __syncthreads();
  if (t < COUT) {
    partials[(size_t)blockIdx.x * (COUT * 2) + t] = sSum[t];
    partials[(size_t)blockIdx.x * (COUT * 2) + COUT + t] = sSq[t];
  }
}

// ------------------------------------------------------------------
// conv2 (MODE 2): staged relu(bn(y1)) GEMM with W2, max/min-pool
// epilogue + layer-2 stat partials.
// ------------------------------------------------------------------
template <int CIN, int COUT, int SPB, int MODE>
__global__ __launch_bounds__(256) void conv_kernel(
    const float* __restrict__ xin, const float* __restrict__ W,
    const float* __restrict__ bias, const float* __restrict__ scaleA,
    const float* __restrict__ shiftA, float* __restrict__ yout,
    float* __restrict__ pmax, float* __restrict__ pmin,
    float* __restrict__ partials) {
  constexpr int WP = COUT + 4;
  constexpr int TPS = (COUT / 4) * 8;
  __shared__ __align__(16) float sW[CIN * WP];
  __shared__ __align__(16) float sX[SPB * CIN * 32];
  __shared__ float sScale[CIN];
  __shared__ float sShift[CIN];
  __shared__ float sSum[COUT];
  __shared__ float sSq[COUT];
  __shared__ float sMax[8 * COUT];
  __shared__ float sMin[8 * COUT];

  const int t = threadIdx.x;
  const int pair0 = blockIdx.x * SPB;

  for (int f = t; f < CIN * COUT; f += 256) {
    int o = f / CIN;
    int c = f - o * CIN;
    sW[c * WP + o] = W[f];
  }
  if (t < CIN) { sScale[t] = scaleA[t]; sShift[t] = shiftA[t]; }
  if (t < COUT) { sSum[t] = 0.f; sSq[t] = 0.f; }
  __syncthreads();

  for (int f = t; f < SPB * CIN * 32; f += 256) {
    int c = (f >> 5) % CIN;
    float v = xin[(size_t)pair0 * CIN * 32 + f];
    v = v * sScale[c] + sShift[c];
    sX[f] = fmaxf(v, 0.f);
  }
  __syncthreads();

  const int sl = t / TPS;
  const int tl = t - sl * TPS;
  const int k0 = (tl & 7) * 4;
  const int o0 = (tl >> 3) * 4;

  float acc[4][4];
#pragma unroll
  for (int i = 0; i < 4; ++i)
#pragma unroll
    for (int j = 0; j < 4; ++j) acc[i][j] = 0.f;

  const float* xrow = sX + sl * (CIN * 32);
#pragma unroll 4
  for (int c = 0; c < CIN; ++c) {
    float4 xv = *(const float4*)(xrow + c * 32 + k0);
    float4 wv = *(const float4*)(sW + c * WP + o0);
    float xa[4] = {xv.x, xv.y, xv.z, xv.w};
    float wa[4] = {wv.x, wv.y, wv.z, wv.w};
#pragma unroll
    for (int i = 0; i < 4; ++i)
#pragma unroll
      for (int j = 0; j < 4; ++j) acc[i][j] += wa[i] * xa[j];
  }
#pragma unroll
  for (int i = 0; i < 4; ++i) {
    float bo = bias[o0 + i];
#pragma unroll
    for (int j = 0; j < 4; ++j) acc[i][j] += bo;
  }
#pragma unroll
  for (int i = 0; i < 4; ++i) {
    float s1 = (acc[i][0] + acc[i][1]) + (acc[i][2] + acc[i][3]);
    float s2 = (acc[i][0] * acc[i][0] + acc[i][1] * acc[i][1]) +
               (acc[i][2] * acc[i][2] + acc[i][3] * acc[i][3]);
    DPP_FADD(s1, 0x111)
    DPP_FADD(s1, 0x112)
    DPP_FADD(s1, 0x114)
    DPP_FADD(s2, 0x111)
    DPP_FADD(s2, 0x112)
    DPP_FADD(s2, 0x114)
    if ((t & 7) == 7) {
      atomicAdd(&sSum[o0 + i], s1);
      atomicAdd(&sSq[o0 + i], s2);
    }
  }
  if (MODE < 2) {
#pragma unroll
    for (int i = 0; i < 4; ++i) {
      float4 v = make_float4(acc[i][0], acc[i][1], acc[i][2], acc[i][3]);
      *(float4*)(yout + (size_t)(pair0 + sl) * COUT * 32 + (o0 + i) * 32 + k0) = v;
    }
  } else {
#pragma unroll
    for (int i = 0; i < 4; ++i) {
      float mx = fmaxf(fmaxf(acc[i][0], acc[i][1]), fmaxf(acc[i][2], acc[i][3]));
      float mn = fminf(fminf(acc[i][0], acc[i][1]), fminf(acc[i][2], acc[i][3]));
      sMax[(k0 >> 2) * COUT + o0 + i] = mx;
      sMin[(k0 >> 2) * COUT + o0 + i] = mn;
    }
  }
  __syncthreads();
  if (t < COUT) {
    partials[(size_t)blockIdx.x * (COUT * 2) + t] = sSum[t];
    partials[(size_t)blockIdx.x * (COUT * 2) + COUT + t] = sSq[t];
    if (MODE == 2) {
      float mx = sMax[t];
      float mn = sMin[t];
#pragma unroll
      for (int q = 1; q < 8; ++q) {
        mx = fmaxf(mx, sMax[q * COUT + t]);
        mn = fminf(mn, sMin[q * COUT + t]);
      }
      pmax[pair0 * COUT + t] = mx;
      pmin[pair0 * COUT + t] = mn;
    }
  }
}

// one block per channel: f64 reduce -> fused scale/shift for next layer
template <int COUT>
__global__ __launch_bounds__(256) void stats_kernel(const float* __restrict__ partials,
                                                    int nblocks,
                                                    const float* __restrict__ gA,
                                                    const float* __restrict__ btA,
                                                    float* __restrict__ scaleA,
                                                    float* __restrict__ shiftA) {
  const int o = blockIdx.x;
  const int t = threadIdx.x;
  double s1 = 0.0, s2 = 0.0;
  for (int blk = t; blk < nblocks; blk += 256) {
    s1 += (double)partials[(size_t)blk * (COUT * 2) + o];
    s2 += (double)partials[(size_t)blk * (COUT * 2) + COUT + o];
  }
  __shared__ double r1[256], r2[256];
  r1[t] = s1; r2[t] = s2;
  __syncthreads();
  for (int st = 128; st > 0; st >>= 1) {
    if (t < st) { r1[t] += r1[t + st]; r2[t] += r2[t + st]; }
    __syncthreads();
  }
  if (t == 0) {
    const double Nr = 262144.0;  // B*K*S
    double mean = r1[0] / Nr;
    double var = r2[0] / Nr - mean * mean;
    double rstd = 1.0 / sqrt(var + 1e-5);
    double sc = rstd * (double)gA[o];
    scaleA[o] = (float)sc;
    shiftA[o] = (float)((double)btA[o] - mean * sc);
  }
}

// layer-2 stats + final normalize fused: one block per channel (128).
__global__ __launch_bounds__(256) void stats_final_kernel(
    const float* __restrict__ partials, int nblocks,
    const float* __restrict__ pmax, const float* __restrict__ pmin,
    const float* __restrict__ gA, const float* __restrict__ btA,
    float* __restrict__ out) {
  const int o = blockIdx.x;
  const int t = threadIdx.x;
  double s1 = 0.0, s2 = 0.0;
  for (int blk = t; blk < nblocks; blk += 256) {
    s1 += (double)partials[(size_t)blk * 256 + o];
    s2 += (double)partials[(size_t)blk * 256 + 128 + o];
  }
  __shared__ double r1[256], r2[256];
  __shared__ float sMean, sRstd;
  r1[t] = s1; r2[t] = s2;
  __syncthreads();
  for (int st = 128; st > 0; st >>= 1) {
    if (t < st) { r1[t] += r1[t + st]; r2[t] += r2[t + st]; }
    __syncthreads();
  }
  if (t == 0) {
    const double Nr = 262144.0;
    double mean = r1[0] / Nr;
    double var = r2[0] / Nr - mean * mean;
    sMean = (float)mean;
    sRstd = (float)(1.0 / sqrt(var + 1e-5));
  }
  __syncthreads();
  const float mn = sMean, rs = sRstd, gg = gA[o], bb = btA[o];
  const float slope = rs * gg;
  const float* src = (slope >= 0.f) ? pmax : pmin;
  for (int i = t; i < NB * NS; i += 256) {
    int b = i >> 10;
    int s = i & 1023;
    float v = src[(size_t)i * 128 + o];
    float t1 = (v - mn) * rs;
    float t2 = t1 * gg + bb;
    out[(size_t)b * (128 * NS) + o * NS + s] = fmaxf(t2, 0.f);
  }
}

extern "C" void kernel_launch(void* const* d_in, const int* in_sizes, int n_in,
                              void* d_out, int out_size, void* d_ws, size_t ws_size,
                              hipStream_t stream) {
  (void)in_sizes; (void)n_in; (void)out_size; (void)ws_size;
  const float* xyz = (const float*)d_in[0];
  const float* points = (const float*)d_in[1];
  const float* W0 = (const float*)d_in[2];
  const float* b0 = (const float*)d_in[3];
  const float* g0 = (const float*)d_in[4];
  const float* bt0 = (const float*)d_in[5];
  const float* W1 = (const float*)d_in[6];
  const float* b1 = (const float*)d_in[7];
  const float* g1 = (const float*)d_in[8];
  const float* bt1 = (const float*)d_in[9];
  const float* W2 = (const float*)d_in[10];
  const float* b2 = (const float*)d_in[11];
  const float* g2 = (const float*)d_in[12];
  const float* bt2 = (const float*)d_in[13];
  float* out = (float*)d_out;

  float* ws = (float*)d_ws;
  size_t off = 0;
  float* newxyz = ws + off;  off += (size_t)NB * NS * 3;
  int* idx = (int*)(ws + off); off += (size_t)NB * NS * NK;
  float* P1 = ws + off;      off += (size_t)NB * NPTS * 64;       // 2M floats
  float* y1 = ws + off;      off += (size_t)NB * NS * 64 * 32;    // 16.8M floats
  float* partials = ws + off; off += (size_t)8192 * 256;
  float* scaleA = ws + off;  off += 128;
  float* shiftA = ws + off;  off += 128;
  float* pmaxb = ws + off;   off += (size_t)NB * NS * 128;
  float* pminb = ws + off;   off += (size_t)NB * NS * 128;

  // blocks 0-7: fps (8 CUs); blocks 8-519: pgemm hidden on idle CUs
  fps_pgemm_kernel<<<520, 512, 0, stream>>>(xyz, out, newxyz, points, W0, b0, P1);
  query_gstats_kernel<<<2048, 256, 0, stream>>>(xyz, newxyz, P1, W0, idx, partials);
  stats_kernel<64><<<64, 256, 0, stream>>>(partials, 2048, g0, bt0, scaleA, shiftA);
  conv1_kernel<<<4096, 256, 0, stream>>>(xyz, P1, idx, newxyz, W0, W1, b1,
                                         scaleA, shiftA, y1, partials);
  stats_kernel<64><<<64, 256, 0, stream>>>(partials, 4096, g1, bt1, scaleA, shiftA);
  conv_kernel<64, 128, 1, 2><<<8192, 256, 0, stream>>>(
      y1, W2, b2, scaleA, shiftA, nullptr, pmaxb, pminb, partials);
  stats_final_kernel<<<128, 256, 0, stream>>>(partials, 8192, pmaxb, pminb,
                                              g2, bt2, out + NB * NS * 3);
}